// Round 12
// baseline (252.656 us; speedup 1.0000x reference)
//
#include <hip/hip_runtime.h>
#include <hip/hip_bf16.h>

// x:[16,64,128,128] f32 -> stats -> MLP -> per-sample kern[64,64,3,3] -> conv(pad=1)
// R12: ONE persistent kernel, 256 blocks x 512 thr (1/CU, all co-resident),
// manual grid barrier (atomic arrive + spin, agent-scope fences for cross-XCD
// part/wT visibility). Phase A = xpose+stats (R3 internals), Phase B = kern_gen
// (R9 internals, 72 blocks), Phase C = conv (R9 ring-buffered MFMA, verbatim).
// b = blk&15 in all phases -> xT traffic stays on XCD b%8.

#define B_ 16
#define NPIX 16384
#define KEL 36864
#define XT_RS 8320          // 130 * 64 shorts per padded row

typedef __attribute__((ext_vector_type(4))) float f32x4;
typedef __attribute__((ext_vector_type(8))) short short8;

static __device__ __forceinline__ short bf16_of(float f) {
    __hip_bfloat16 h = __float2bfloat16(f);
    return *reinterpret_cast<short*>(&h);
}

static __device__ __forceinline__ void grid_barrier(unsigned* cnt, unsigned tgt) {
    __syncthreads();
    __threadfence();                       // release: wbl2 (flush dirty L2 to L3)
    if (threadIdx.x == 0) {
        __hip_atomic_fetch_add(cnt, 1u, __ATOMIC_ACQ_REL, __HIP_MEMORY_SCOPE_AGENT);
        while (__hip_atomic_load(cnt, __ATOMIC_ACQUIRE, __HIP_MEMORY_SCOPE_AGENT) < tgt)
            __builtin_amdgcn_s_sleep(2);
    }
    __syncthreads();
    __threadfence();                       // acquire: inv L1/L2 stale copies
}

__global__ __launch_bounds__(512) void fused(const float* __restrict__ x,
                                             const float* __restrict__ w1,
                                             const float* __restrict__ b1,
                                             const float* __restrict__ w2,
                                             const float* __restrict__ b2,
                                             unsigned* cnt,
                                             float* __restrict__ part,
                                             short* __restrict__ wT,
                                             short* __restrict__ xT,
                                             float* __restrict__ out) {
    __shared__ __align__(16) char smem[158208];
    int t = threadIdx.x;
    int blk = blockIdx.x;                  // 0..255

    // ================= Phase A: transpose + stats =================
    // blk -> (b = blk&15, cig = (blk>>4)&7, half = blk>>7); 64 rows x 128 x x 8 ci.
    {
        int b = blk & 15, cig = (blk >> 4) & 7, half = blk >> 7;
        const float* xb = x + ((size_t)(b * 64 + cig * 8)) * NPIX;
        short* xTb = xT + (size_t)b * 128 * XT_RS;

        float s[8], ss[8];
        #pragma unroll
        for (int c = 0; c < 8; c++) { s[c] = 0.f; ss[c] = 0.f; }
        int yl = t >> 5, x0 = (t & 31) * 4;

        #pragma unroll 1
        for (int yo = 0; yo < 4; yo++) {
            int y = half * 64 + yo * 16 + yl;
            f32x4 v[8];
            #pragma unroll
            for (int c = 0; c < 8; c++) {
                v[c] = *(const f32x4*)(xb + (size_t)c * NPIX + y * 128 + x0);
                s[c]  += v[c][0] + v[c][1] + v[c][2] + v[c][3];
                ss[c] += v[c][0]*v[c][0] + v[c][1]*v[c][1] + v[c][2]*v[c][2] + v[c][3]*v[c][3];
            }
            #pragma unroll
            for (int xi = 0; xi < 4; xi++) {
                short8 o;
                #pragma unroll
                for (int c = 0; c < 8; c++) o[c] = bf16_of(v[c][xi]);
                *(short8*)(xTb + ((size_t)(y * 130 + x0 + xi + 1)) * 64 + cig * 8) = o;
            }
        }
        // zero-pad columns xi=0 and xi=129 for this (b,cig,64-row half)
        if (t < 128) {
            int y2 = half * 64 + (t & 63);
            int col = (t >> 6) ? 129 : 0;
            short8 z = {0, 0, 0, 0, 0, 0, 0, 0};
            *(short8*)(xTb + ((size_t)(y2 * 130 + col)) * 64 + cig * 8) = z;
        }

        float* red = (float*)smem;         // [8 waves][16]
        int lane = t & 63, w = t >> 6;
        #pragma unroll
        for (int c = 0; c < 8; c++) {
            float a = s[c], q = ss[c];
            for (int off = 32; off; off >>= 1) { a += __shfl_down(a, off); q += __shfl_down(q, off); }
            if (lane == 0) { red[w * 16 + c * 2] = a; red[w * 16 + c * 2 + 1] = q; }
        }
        __syncthreads();
        if (t < 16) {
            float a = 0.f;
            #pragma unroll
            for (int w2i = 0; w2i < 8; w2i++) a += red[w2i * 16 + t];
            part[(size_t)(b * 8 + cig) * 32 + half * 16 + t] = a;
        }
    }
    grid_barrier(cnt, 256);

    // ================= Phase B: MLP + weight gen (blocks 0..71) =================
    if (blk < 72) {
        float* st = (float*)smem;                  // [16][128]
        float* hT = (float*)(smem + 8192);         // [32][16]
        for (int id = t; id < 1024; id += 512) {
            int b = id >> 6, ci = id & 63;
            float s = 0.f, q = 0.f;
            #pragma unroll
            for (int hh = 0; hh < 2; hh++) {
                const float* pb = part + (size_t)(b * 8 + (ci >> 3)) * 32 + hh * 16 + (ci & 7) * 2;
                s += pb[0]; q += pb[1];
            }
            float mean = s * (1.f / NPIX);
            float var = fmaxf((q - s * mean) * (1.f / (NPIX - 1)), 0.f);
            st[b * 128 + ci] = mean;
            st[b * 128 + 64 + ci] = sqrtf(var);
        }
        __syncthreads();
        {
            int b = t >> 5, jj = t & 31;
            float acc = b1[jj];
            for (int i = 0; i < 128; i++) acc += st[b * 128 + i] * w1[i * 32 + jj];
            hT[jj * 16 + b] = fmaxf(acc, 0.f);
        }
        __syncthreads();

        int j = blk * 512 + t;
        float wv[32];
        #pragma unroll
        for (int i = 0; i < 32; i++) wv[i] = w2[(size_t)i * KEL + j];
        float bv = b2[j];

        float acc[16];
        #pragma unroll
        for (int b = 0; b < 16; b++) acc[b] = bv;
        #pragma unroll
        for (int i = 0; i < 32; i++) {
            float wvi = wv[i];
            const f32x4* hr = (const f32x4*)&hT[i * 16];
            #pragma unroll
            for (int q4 = 0; q4 < 4; q4++) {
                f32x4 hq = hr[q4];
                acc[q4 * 4 + 0] += hq[0] * wvi;
                acc[q4 * 4 + 1] += hq[1] * wvi;
                acc[q4 * 4 + 2] += hq[2] * wvi;
                acc[q4 * 4 + 3] += hq[3] * wvi;
            }
        }
        // j = (co*64+ci)*9 + tap; pre-swizzled: [tap][co][ (ci>>3)^(co&7) slot ]
        int co = j / 576;
        int rem = j - co * 576;
        int ci = rem / 9;
        int tap = rem - ci * 9;
        size_t dst = (size_t)tap * 4096 + co * 64 + ((((ci >> 3) ^ (co & 7)) << 3) | (ci & 7));
        #pragma unroll
        for (int b = 0; b < 16; b++)
            wT[(size_t)b * KEL + dst] = bf16_of(acc[b]);
    }
    grid_barrier(cnt, 512);

    // ================= Phase C: conv (R9 ring-buffered MFMA) =================
    {
        short* xls = (short*)smem;                 // 10*528*8 shorts = 84480 B
        short* wls = (short*)(smem + 84480);       // 9*512*8 shorts = 73728 B

        int b = blk & 15, xt = (blk >> 4) & 1, ytg = blk >> 5;
        int x0 = xt * 64, Y0 = ytg * 16;
        int l = t & 63, w = t >> 6;
        int ch = w & 1, r = w >> 1;
        int l15 = l & 15, lg = l >> 4;

        const short* xTb = xT + (size_t)b * 128 * XT_RS;
        const short* wTb = wT + (size_t)b * KEL;

#define ZROW(sl_)                                                              \
    {   short8 z8 = {0, 0, 0, 0, 0, 0, 0, 0};                                  \
        for (int e = t; e < 528; e += 512)                                     \
            *(short8*)(xls + ((sl_) * 528 + e) * 8) = z8; }

#define DMAROW(sl_, y_)                                                        \
    {   _Pragma("unroll")                                                      \
        for (int it = 0; it < 2; it++) {                                       \
            int e = it * 512 + t;                                              \
            if (e < 528) {                                                     \
                int xi = e >> 3, sl8 = e & 7;                                  \
                const short* src = xTb + (size_t)(y_) * XT_RS                  \
                    + (x0 + xi) * 64 + ((sl8 ^ (xi & 7)) << 3);                \
                __builtin_amdgcn_global_load_lds(                              \
                    (const __attribute__((address_space(1))) void*)src,        \
                    (__attribute__((address_space(3))) void*)                   \
                        (xls + ((sl_) * 528 + it * 512 + (t & ~63)) * 8),      \
                    16, 0, 0);                                                 \
            }                                                                  \
        } }

        // stage wls (pure linear DMA, wT pre-swizzled)
        #pragma unroll
        for (int it = 0; it < 9; it++) {
            int e = it * 512 + t;
            __builtin_amdgcn_global_load_lds(
                (const __attribute__((address_space(1))) void*)(wTb + (size_t)e * 8),
                (__attribute__((address_space(3))) void*)(wls + (it * 512 + (t & ~63)) * 8),
                16, 0, 0);
        }
        // prologue: rows Y0-1 .. Y0+4 into slots 0..5
        #pragma unroll
        for (int k = 0; k < 6; k++) {
            int y = Y0 - 1 + k;
            if (y < 0) { ZROW(k); } else { DMAROW(k, y); }
        }
        asm volatile("s_waitcnt vmcnt(0)" ::: "memory");
        __syncthreads();

        int rbase = 0;
        #pragma unroll 1
        for (int j = 0; j < 4; j++) {
            if (j < 3) {
                #pragma unroll
                for (int m = 0; m < 4; m++) {
                    int sl = rbase + 6 + m; if (sl >= 10) sl -= 10;
                    int y = Y0 + 4 * j + 5 + m;
                    if (y > 127) { ZROW(sl); } else { DMAROW(sl, y); }
                }
            }

            int y0 = Y0 + 4 * j;
            f32x4 acc[4][2];
            #pragma unroll
            for (int n = 0; n < 4; n++)
                #pragma unroll
                for (int g = 0; g < 2; g++) acc[n][g] = (f32x4){0.f, 0.f, 0.f, 0.f};

            #pragma unroll
            for (int kp = 0; kp < 2; kp++) {
                int sig = kp * 4 + lg;
                int pa = sig ^ (l15 & 7);
                #pragma unroll
                for (int tap = 0; tap < 9; tap++) {
                    const int dy = tap / 3, dx = tap % 3;
                    int sl = rbase + r + dy; if (sl >= 10) sl -= 10;
                    short8 a0 = *(const short8*)&wls[(tap * 512 + (ch * 32 + l15) * 8 + pa) * 8];
                    short8 a1 = *(const short8*)&wls[(tap * 512 + (ch * 32 + 16 + l15) * 8 + pa) * 8];
                    #pragma unroll
                    for (int n = 0; n < 4; n++) {
                        int xi = n * 16 + l15 + dx;
                        short8 bf = *(const short8*)&xls[(sl * 528 + xi * 8 + (sig ^ (xi & 7))) * 8];
                        acc[n][0] = __builtin_amdgcn_mfma_f32_16x16x32_bf16(a0, bf, acc[n][0], 0, 0, 0);
                        acc[n][1] = __builtin_amdgcn_mfma_f32_16x16x32_bf16(a1, bf, acc[n][1], 0, 0, 0);
                    }
                }
            }

            #pragma unroll
            for (int g = 0; g < 2; g++) {
                float* ob = out + ((size_t)(b * 64 + ch * 32 + g * 16 + lg * 4)) * NPIX
                                + (y0 + r) * 128 + x0 + l15;
                #pragma unroll
                for (int reg = 0; reg < 4; reg++)
                    #pragma unroll
                    for (int n = 0; n < 4; n++)
                        ob[(size_t)reg * NPIX + n * 16] = acc[n][g][reg];
            }

            if (j < 3) {
                asm volatile("s_waitcnt vmcnt(0)" ::: "memory");
                __syncthreads();
            }
            rbase += 4; if (rbase >= 10) rbase -= 10;
        }
#undef ZROW
#undef DMAROW
    }
}

extern "C" void kernel_launch(void* const* d_in, const int* in_sizes, int n_in,
                              void* d_out, int out_size, void* d_ws, size_t ws_size,
                              hipStream_t stream) {
    const float* x  = (const float*)d_in[0];
    const float* w1 = (const float*)d_in[1];
    const float* b1 = (const float*)d_in[2];
    const float* w2 = (const float*)d_in[3];
    const float* b2 = (const float*)d_in[4];
    float* out = (float*)d_out;

    unsigned* cnt = (unsigned*)d_ws;                                   // 4 KB (counter)
    float* part = (float*)((char*)d_ws + 4096);                        // 16 KB
    short* wT = (short*)((char*)d_ws + 4096 + 16384);                  // 1.18 MB
    short* xT = (short*)((char*)d_ws + 4096 + 16384 + 1179648);        // 34.1 MB

    hipMemsetAsync(d_ws, 0, 256, stream);
    fused<<<dim3(256), dim3(512), 0, stream>>>(x, w1, b1, w2, b2, cnt, part, wT, xT, out);
}

// Round 13
// 65.820 us; speedup vs baseline: 3.8386x; 3.8386x over previous
//
#include <hip/hip_runtime.h>
#include <hip/hip_bf16.h>

// x:[16,64,128,128] f32 -> stats -> MLP -> per-sample kern[64,64,3,3] -> conv(pad=1)
// bf16 MFMA implicit GEMM. xT[b][y][130 xi][64 ci] bf16 (x-padded zero cols).
// wT layout: [b][tap(9)][co(64)][64 ci, 16B-slot s stored at s^(co&7)].
// R13: back to 3 kernels (R12 fusion failed: wrong occupancy per phase).
// conv shrunk to 32px x 8row x 32co blocks -> LDS 80384 B -> 2 RESIDENT
// blocks/CU, 8 sequential blocks/CU: cross-block stage||compute overlap,
// weights stay in LDS (allocator-proof). kern_gen widened to 288 blocks.

#define B_ 16
#define NPIX 16384
#define KEL 36864
#define XT_RS 8320          // 130 * 64 shorts per padded row

typedef __attribute__((ext_vector_type(4))) float f32x4;
typedef __attribute__((ext_vector_type(8))) short short8;

static __device__ __forceinline__ short bf16_of(float f) {
    __hip_bfloat16 h = __float2bfloat16(f);
    return *reinterpret_cast<short*>(&h);
}

// ---------- Kernel 1: transpose x -> xT bf16 [b][y][130][64]; partial stats ----------
__global__ __launch_bounds__(256) void xpose_stats(const float* __restrict__ x,
                                                   short* __restrict__ xT,
                                                   float* __restrict__ part) {
    int b = blockIdx.x, cig = blockIdx.y, pt = blockIdx.z;
    int t = threadIdx.x;
    int y = pt * 8 + (t >> 5);
    int x0 = (t & 31) * 4;

    const float* xb = x + ((size_t)(b * 64 + cig * 8)) * NPIX;
    short* xTb = xT + (size_t)b * 128 * XT_RS;

    float s[8], ss[8];
    f32x4 v[8];
    #pragma unroll
    for (int c = 0; c < 8; c++) {
        v[c] = *(const f32x4*)(xb + (size_t)c * NPIX + y * 128 + x0);
        s[c]  = v[c][0] + v[c][1] + v[c][2] + v[c][3];
        ss[c] = v[c][0]*v[c][0] + v[c][1]*v[c][1] + v[c][2]*v[c][2] + v[c][3]*v[c][3];
    }
    #pragma unroll
    for (int xi = 0; xi < 4; xi++) {
        short8 o;
        #pragma unroll
        for (int c = 0; c < 8; c++) o[c] = bf16_of(v[c][xi]);
        *(short8*)(xTb + ((size_t)(y * 130 + x0 + xi + 1)) * 64 + cig * 8) = o;
    }
    // zero-pad columns xi=0 and xi=129 (x halo)
    if (t < 16) {
        int y2 = pt * 8 + (t & 7);
        int col = (t & 8) ? 129 : 0;
        short8 z = {0, 0, 0, 0, 0, 0, 0, 0};
        *(short8*)(xTb + ((size_t)(y2 * 130 + col)) * 64 + cig * 8) = z;
    }

    __shared__ float red[4][16];
    int lane = t & 63, w = t >> 6;
    #pragma unroll
    for (int c = 0; c < 8; c++) {
        float a = s[c], q = ss[c];
        for (int off = 32; off; off >>= 1) { a += __shfl_down(a, off); q += __shfl_down(q, off); }
        if (lane == 0) { red[w][c * 2] = a; red[w][c * 2 + 1] = q; }
    }
    __syncthreads();
    if (t < 16)
        part[((size_t)((b * 8 + cig) * 16 + pt)) * 16 + t] =
            red[0][t] + red[1][t] + red[2][t] + red[3][t];
}

// ---------- Kernel 2: w2 read once per j; grid 288, thread = (j, b-half) ----------
__global__ __launch_bounds__(256) void kern_gen(const float* __restrict__ part,
                                                const float* __restrict__ w1,
                                                const float* __restrict__ b1,
                                                const float* __restrict__ w2,
                                                const float* __restrict__ b2,
                                                short* __restrict__ wT) {
    __shared__ float st[16][128];
    __shared__ float hT[32][16];
    int t = threadIdx.x;

    for (int id = t; id < 1024; id += 256) {       // stats for all (b, ci)
        int b = id >> 6, ci = id & 63;
        const float* pb = part + ((size_t)((b * 8 + (ci >> 3)) * 16)) * 16 + (ci & 7) * 2;
        float s = 0.f, q = 0.f;
        #pragma unroll
        for (int p = 0; p < 16; p++) { s += pb[p * 16]; q += pb[p * 16 + 1]; }
        float mean = s * (1.f / NPIX);
        float var = fmaxf((q - s * mean) * (1.f / (NPIX - 1)), 0.f);
        st[b][ci] = mean;
        st[b][64 + ci] = sqrtf(var);
    }
    __syncthreads();
    for (int id = t; id < 512; id += 256) {        // h for all (b, 32), transposed
        int b = id >> 5, jj = id & 31;
        float acc = b1[jj];
        for (int i = 0; i < 128; i++) acc += st[b][i] * w1[i * 32 + jj];
        hT[jj][b] = fmaxf(acc, 0.f);
    }
    __syncthreads();

    int j = blockIdx.x * 128 + (t & 127);
    int bh = t >> 7;                               // b-half 0/1
    float wv[32];
    #pragma unroll
    for (int i = 0; i < 32; i++) wv[i] = w2[(size_t)i * KEL + j];
    float bv = b2[j];

    float acc[8];
    #pragma unroll
    for (int k = 0; k < 8; k++) acc[k] = bv;
    #pragma unroll
    for (int i = 0; i < 32; i++) {
        float wvi = wv[i];
        const f32x4* hr = (const f32x4*)&hT[i][bh * 8];
        #pragma unroll
        for (int q4 = 0; q4 < 2; q4++) {
            f32x4 hq = hr[q4];
            acc[q4 * 4 + 0] += hq[0] * wvi;
            acc[q4 * 4 + 1] += hq[1] * wvi;
            acc[q4 * 4 + 2] += hq[2] * wvi;
            acc[q4 * 4 + 3] += hq[3] * wvi;
        }
    }

    // j = (co*64+ci)*9 + tap; pre-swizzled: [tap][co][ (ci>>3)^(co&7) slot ]
    int co = j / 576;
    int rem = j - co * 576;
    int ci = rem / 9;
    int tap = rem - ci * 9;
    size_t dst = (size_t)tap * 4096 + co * 64 + ((((ci >> 3) ^ (co & 7)) << 3) | (ci & 7));
    #pragma unroll
    for (int k = 0; k < 8; k++)
        wT[(size_t)(bh * 8 + k) * KEL + dst] = bf16_of(acc[k]);
}

// ---------- Kernel 3: conv via MFMA, 2 RESIDENT blocks/CU ----------
// grid (b=16, xt+4*cog=8, ys=16) = 2048 blocks (8/CU, 2 resident), 256 thr (4 waves).
// Block: 32 px x 8 rows x 32 co. Wave (xq=w&1, rh=w>>1): 16 px x 4 rows x 32 co.
// LDS: xls 10 rows x 272 slots x 16B (43520 B) + wls 9 x 256 x 16B (36864 B) = 80384 B.
__global__ __launch_bounds__(256, 2) void conv_mfma(const short* __restrict__ xT,
                                                    const short* __restrict__ wT,
                                                    float* __restrict__ out) {
    __shared__ __align__(16) short xls[10 * 272 * 8];   // slot = row*272 + xi*8 + s
    __shared__ __align__(16) short wls[9 * 256 * 8];    // slot = tap*256 + co_l*8 + s

    int b = blockIdx.x;
    int xt = blockIdx.y & 3, cog = blockIdx.y >> 2;
    int ys = blockIdx.z;
    int x0 = xt * 32, y0 = ys * 8;
    int t = threadIdx.x;
    int l = t & 63, w = t >> 6;
    int xq = w & 1, rh = w >> 1;
    int l15 = l & 15, lg = l >> 4;

    const short* xTb = xT + (size_t)b * 128 * XT_RS;
    const short* wTb = wT + (size_t)b * KEL + cog * 2048;   // 32-co slice within each tap

    // ---- stage wls: 9 taps x 32 co x 64 ci (linear DMA, wT pre-swizzled) ----
    #pragma unroll
    for (int it = 0; it < 9; it++) {
        __builtin_amdgcn_global_load_lds(
            (const __attribute__((address_space(1))) void*)(wTb + (size_t)it * 4096 + t * 8),
            (__attribute__((address_space(3))) void*)(wls + (it * 256 + (t & ~63)) * 8),
            16, 0, 0);
    }
    // ---- stage x rows y0-1 .. y0+8 into slots 0..9 ----
    #pragma unroll
    for (int lr = 0; lr < 10; lr++) {
        int y = y0 - 1 + lr;
        if (y < 0 || y > 127) {
            short8 z8 = {0, 0, 0, 0, 0, 0, 0, 0};
            #pragma unroll
            for (int it = 0; it < 2; it++) {
                int e = it * 256 + t;
                if (e < 272) *(short8*)(xls + (lr * 272 + e) * 8) = z8;
            }
        } else {
            #pragma unroll
            for (int it = 0; it < 2; it++) {
                int e = it * 256 + t;
                if (e < 272) {
                    int xi = e >> 3, s = e & 7;
                    const short* src = xTb + (size_t)y * XT_RS
                        + (x0 + xi) * 64 + ((s ^ (xi & 7)) << 3);
                    __builtin_amdgcn_global_load_lds(
                        (const __attribute__((address_space(1))) void*)src,
                        (__attribute__((address_space(3))) void*)
                            (xls + (lr * 272 + it * 256 + (t & ~63)) * 8),
                        16, 0, 0);
                }
            }
        }
    }
    asm volatile("s_waitcnt vmcnt(0)" ::: "memory");
    __syncthreads();

    f32x4 acc[2][4];                      // [co-frag f][row r]
    #pragma unroll
    for (int f = 0; f < 2; f++)
        #pragma unroll
        for (int r = 0; r < 4; r++) acc[f][r] = (f32x4){0.f, 0.f, 0.f, 0.f};

    #pragma unroll
    for (int kp = 0; kp < 2; kp++) {
        int sig = kp * 4 + lg;
        int pa = sig ^ (l15 & 7);
        #pragma unroll
        for (int tap = 0; tap < 9; tap++) {
            const int dy = tap / 3, dx = tap % 3;
            short8 a0 = *(const short8*)&wls[(tap * 256 + l15 * 8 + pa) * 8];
            short8 a1 = *(const short8*)&wls[(tap * 256 + (16 + l15) * 8 + pa) * 8];
            int xi = xq * 16 + l15 + dx;                 // 0..33
            int sw = sig ^ (xi & 7);
            #pragma unroll
            for (int r = 0; r < 4; r++) {
                int row = rh * 4 + r + dy;               // 0..9
                short8 bf = *(const short8*)&xls[(row * 272 + xi * 8 + sw) * 8];
                acc[0][r] = __builtin_amdgcn_mfma_f32_16x16x32_bf16(a0, bf, acc[0][r], 0, 0, 0);
                acc[1][r] = __builtin_amdgcn_mfma_f32_16x16x32_bf16(a1, bf, acc[1][r], 0, 0, 0);
            }
        }
    }

    // ---- store: 2 co-frags x 4 regs x 4 rows x 16 px ----
    #pragma unroll
    for (int f = 0; f < 2; f++) {
        #pragma unroll
        for (int reg = 0; reg < 4; reg++) {
            float* ob = out + ((size_t)(b * 64 + cog * 32 + f * 16 + lg * 4 + reg)) * NPIX
                            + (y0 + rh * 4) * 128 + x0 + xq * 16 + l15;
            #pragma unroll
            for (int r = 0; r < 4; r++)
                ob[r * 128] = acc[f][r][reg];
        }
    }
}

extern "C" void kernel_launch(void* const* d_in, const int* in_sizes, int n_in,
                              void* d_out, int out_size, void* d_ws, size_t ws_size,
                              hipStream_t stream) {
    const float* x  = (const float*)d_in[0];
    const float* w1 = (const float*)d_in[1];
    const float* b1 = (const float*)d_in[2];
    const float* w2 = (const float*)d_in[3];
    const float* b2 = (const float*)d_in[4];
    float* out = (float*)d_out;

    float* part = (float*)d_ws;                                   // 128 KB
    short* wT = (short*)((char*)d_ws + 131072);                   // 1.18 MB
    short* xT = (short*)((char*)d_ws + 131072 + 1179648);         // 34.1 MB

    xpose_stats<<<dim3(B_, 8, 16), 256, 0, stream>>>(x, xT, part);
    kern_gen<<<dim3(288), 256, 0, stream>>>(part, w1, b1, w2, b2, wT);
    conv_mfma<<<dim3(B_, 8, 16), 256, 0, stream>>>(xT, wT, out);
}